// Round 6
// baseline (49.174 us; speedup 1.0000x reference)
//
#include <hip/hip_runtime.h>

// Geometry (from reference): B=4, C=8, D=48, H=128, W=160
#define HW    20480      // H*W
#define DHW   983040     // D*H*W (channel stride)
#define CDHW  7864320    // C*D*H*W (batch stride)
#define NPIX  81920      // B*H*W
#define DCH   4          // d-slices per wave-task
#define NCH   12         // d-chunks (48/DCH)
#define NGRP  640        // pixel groups of 128 px (2 px/lane)
#define NTASK (NGRP * NCH)   // 7680 wave-tasks
#define NBLK  (NTASK / 4)    // 4 waves per block

typedef _Float16 half2v  __attribute__((ext_vector_type(2)));
typedef float    float2v __attribute__((ext_vector_type(2)));

// Folded weights (BN absorbed), f16 pairs stored as uint bit patterns.
__device__ unsigned g_w0u[64];   // [o][i] : o<16, i<4
__device__ float    g_b0[16];
__device__ unsigned g_w1u[64];   // [j][i] : j<8,  i<8
__device__ float    g_b1[8];
__device__ unsigned g_w2u[4];
__device__ float    g_bias2;

static __device__ __forceinline__ float dot2(half2v a, half2v b, float c) {
#if __has_builtin(__builtin_amdgcn_fdot2)
    return __builtin_amdgcn_fdot2(a, b, c, false);
#else
    return fmaf((float)a.x, (float)b.x, fmaf((float)a.y, (float)b.y, c));
#endif
}

static __device__ __forceinline__ half2v pk(float a, float b) {
#if __has_builtin(__builtin_amdgcn_cvt_pkrtz)
    return __builtin_bit_cast(half2v, __builtin_amdgcn_cvt_pkrtz(a, b));
#else
    half2v h; h.x = (_Float16)a; h.y = (_Float16)b; return h;
#endif
}

static __device__ __forceinline__ unsigned pku(float a, float b) {
    return __builtin_bit_cast(unsigned, pk(a, b));
}

// Order-preserving bijection float -> uint (for atomicMax-based fmax).
static __device__ __forceinline__ unsigned enc(float f) {
    unsigned u = __float_as_uint(f);
    return (u & 0x80000000u) ? ~u : (u | 0x80000000u);
}
static __device__ __forceinline__ float dec(unsigned u) {
    unsigned v = (u & 0x80000000u) ? (u & 0x7FFFFFFFu) : ~u;
    return __uint_as_float(v);
}

__global__ void fold_kernel(const float* __restrict__ w0, const float* __restrict__ g0,
                            const float* __restrict__ b0, const float* __restrict__ m0,
                            const float* __restrict__ v0,
                            const float* __restrict__ w1, const float* __restrict__ g1,
                            const float* __restrict__ b1, const float* __restrict__ m1,
                            const float* __restrict__ v1,
                            const float* __restrict__ w2, const float* __restrict__ bias2)
{
    int t = threadIdx.x;
    if (t < 16) {
        float sc = g0[t] * rsqrtf(v0[t] + 1e-5f);
        for (int i = 0; i < 4; ++i)
            g_w0u[t * 4 + i] = pku(w0[t * 8 + 2 * i] * sc, w0[t * 8 + 2 * i + 1] * sc);
        g_b0[t] = b0[t] - m0[t] * sc;
    } else if (t < 24) {
        int j = t - 16;
        float sc = g1[j] * rsqrtf(v1[j] + 1e-5f);
        for (int i = 0; i < 8; ++i)
            g_w1u[j * 8 + i] = pku(w1[j * 16 + 2 * i] * sc, w1[j * 16 + 2 * i + 1] * sc);
        g_b1[j] = b1[j] - m1[j] * sc;
    } else if (t == 24) {
        for (int i = 0; i < 4; ++i)
            g_w2u[i] = pku(w2[2 * i], w2[2 * i + 1]);
        g_bias2 = bias2[0];
    }
}

// One pixel's MLP. xh = 4 packed f16 channel-pairs. Returns logit.
static __device__ __forceinline__ float mlp_px(const half2v xh[4],
                                               const unsigned* w0s, const unsigned* b0s,
                                               const unsigned* w1v, const float* b1v,
                                               const unsigned* w2v, float b2v)
{
    float h0[16];
#pragma unroll
    for (int o = 0; o < 16; ++o) {
        float a = __uint_as_float(b0s[o]);
#pragma unroll
        for (int i = 0; i < 4; ++i)
            a = dot2(xh[i], __builtin_bit_cast(half2v, w0s[o * 4 + i]), a);
        h0[o] = fmaxf(a, 0.0f);
    }
    half2v hh[8];
#pragma unroll
    for (int i = 0; i < 8; ++i) hh[i] = pk(h0[2 * i], h0[2 * i + 1]);
    float h1[8];
#pragma unroll
    for (int j = 0; j < 8; ++j) {
        float a = b1v[j];
#pragma unroll
        for (int i = 0; i < 8; ++i)
            a = dot2(hh[i], __builtin_bit_cast(half2v, w1v[j * 8 + i]), a);
        h1[j] = fmaxf(a, 0.0f);
    }
    half2v hq[4];
#pragma unroll
    for (int i = 0; i < 4; ++i) hq[i] = pk(h1[2 * i], h1[2 * i + 1]);
    float a = b2v;
#pragma unroll
    for (int i = 0; i < 4; ++i)
        a = dot2(hq[i], __builtin_bit_cast(half2v, w2v[i]), a);
    return a;
}

// Kernel A: each wave = one (128-pixel group, 4-slice d-chunk) task.
// Partial max merged into d_out (as monotone uint) via atomicMax.
__global__ __launch_bounds__(256, 3)
void mlp_kernel(const float* __restrict__ x, unsigned* __restrict__ outu)
{
    const int lane = threadIdx.x & 63;
    const int wid  = blockIdx.x * 4 + (threadIdx.x >> 6);  // global wave-task id
    const int g    = wid / NCH;                            // pixel group
    const int ch   = wid - g * NCH;                        // d-chunk
    const int b    = g / 160;
    const int s0   = (g - b * 160) * 128 + lane * 2;
    const float* xp = x + (size_t)b * CDHW + s0 + (size_t)(ch * DCH) * HW;

    // Layer-0 weights + biases -> SGPRs (wave-uniform; dot2 takes scalar src).
    unsigned w0s[64]; unsigned b0s[16];
#pragma unroll
    for (int k = 0; k < 64; ++k) {
        w0s[k] = __builtin_amdgcn_readfirstlane(g_w0u[k]);
        asm("" : "+s"(w0s[k]));
    }
#pragma unroll
    for (int k = 0; k < 16; ++k) {
        b0s[k] = __builtin_amdgcn_readfirstlane(__float_as_uint(g_b0[k]));
        asm("" : "+s"(b0s[k]));
    }
    // Layer-1/2 weights -> VGPRs.
    unsigned w1v[64]; float b1v[8]; unsigned w2v[4]; float b2v;
#pragma unroll
    for (int k = 0; k < 64; ++k) { w1v[k] = g_w1u[k]; asm("" : "+v"(w1v[k])); }
#pragma unroll
    for (int k = 0; k < 8; ++k)  { b1v[k] = g_b1[k];  asm("" : "+v"(b1v[k])); }
#pragma unroll
    for (int k = 0; k < 4; ++k)  { w2v[k] = g_w2u[k]; asm("" : "+v"(w2v[k])); }
    b2v = g_bias2; asm("" : "+v"(b2v));

    float maxv0 = -1e30f, maxv1 = -1e30f;

    // Current slice packed: c0 = pixel lane*2, c1 = pixel lane*2+1.
    half2v c0[4], c1[4];
    {
        float2v ld[8];
#pragma unroll
        for (int c = 0; c < 8; ++c) ld[c] = *(const float2v*)(xp + (size_t)c * DHW);
#pragma unroll
        for (int i = 0; i < 4; ++i) {
            c0[i] = pk(ld[2 * i].x, ld[2 * i + 1].x);
            c1[i] = pk(ld[2 * i].y, ld[2 * i + 1].y);
        }
    }

#pragma unroll
    for (int d = 0; d < DCH; ++d) {
        float2v nx[8];
        if (d + 1 < DCH) {
            const float* xq = xp + (size_t)(d + 1) * HW;
#pragma unroll
            for (int c = 0; c < 8; ++c) nx[c] = *(const float2v*)(xq + (size_t)c * DHW);
        }

        maxv0 = fmaxf(maxv0, mlp_px(c0, w0s, b0s, w1v, b1v, w2v, b2v));
        maxv1 = fmaxf(maxv1, mlp_px(c1, w0s, b0s, w1v, b1v, w2v, b2v));

        if (d + 1 < DCH) {
#pragma unroll
            for (int i = 0; i < 4; ++i) {
                c0[i] = pk(nx[2 * i].x, nx[2 * i + 1].x);
                c1[i] = pk(nx[2 * i].y, nx[2 * i + 1].y);
            }
        }
    }

    unsigned* po = outu + (size_t)g * 128 + lane * 2;
    atomicMax(po,     enc(maxv0));
    atomicMax(po + 1, enc(maxv1));
}

// Kernel B: decode uint -> logit, apply sigmoid, write float in place.
__global__ __launch_bounds__(256)
void finish_kernel(unsigned* __restrict__ outu)
{
    int i = blockIdx.x * 256 + threadIdx.x;
    if (i < NPIX) {
        float m = dec(outu[i]);
        ((float*)outu)[i] = 1.0f / (1.0f + __expf(-m));
    }
}

extern "C" void kernel_launch(void* const* d_in, const int* in_sizes, int n_in,
                              void* d_out, int out_size, void* d_ws, size_t ws_size,
                              hipStream_t stream) {
    const float* x1 = (const float*)d_in[0];
    unsigned* outu = (unsigned*)d_out;

    // enc() of any finite logit is > 0, so 0 is a safe "-inf" for atomicMax.
    hipMemsetAsync(d_out, 0, (size_t)NPIX * 4, stream);

    fold_kernel<<<1, 64, 0, stream>>>(
        (const float*)d_in[1], (const float*)d_in[2], (const float*)d_in[3],
        (const float*)d_in[4], (const float*)d_in[5],
        (const float*)d_in[6], (const float*)d_in[7], (const float*)d_in[8],
        (const float*)d_in[9], (const float*)d_in[10],
        (const float*)d_in[11], (const float*)d_in[12]);

    mlp_kernel<<<NBLK, 256, 0, stream>>>(x1, outu);
    finish_kernel<<<(NPIX + 255) / 256, 256, 0, stream>>>(outu);
}